// Round 17
// baseline (213.898 us; speedup 1.0000x reference)
//
#include <hip/hip_runtime.h>
#include <hip/hip_bf16.h>
#include <stdint.h>

// Shapes
#define DIM      1024
#define D_STATE  16
#define D_CONV   4
#define D_INNER  2048
#define DT_RANK  64
#define BATCH    2
#define SEQ      1024
#define MROWS    (BATCH * SEQ)            // 2048
#define NPROJ    (2 * D_INNER)            // 4096
#define XDBL_K   (DT_RANK + 2 * D_STATE)  // 96

// chunked scan
#define LC       16
#define NC       (SEQ / LC)               // 64
#define SLANES   (BATCH * D_INNER * D_STATE) // 65536

typedef __attribute__((ext_vector_type(8))) short short8;
typedef __attribute__((ext_vector_type(4))) float f32x4;
typedef unsigned short ushort_t;

__device__ __forceinline__ unsigned short f2bf(float f) {
    __hip_bfloat16 b = __float2bfloat16(f);
    return *reinterpret_cast<unsigned short*>(&b);
}
__device__ __forceinline__ float bf2f(unsigned short u) {
    __hip_bfloat16 b;
    *reinterpret_cast<unsigned short*>(&b) = u;
    return __bfloat162float(b);
}

__device__ __forceinline__ void gload_lds16(const unsigned short* g, unsigned short* l) {
    __builtin_amdgcn_global_load_lds(
        (const __attribute__((address_space(1))) void*)g,
        (__attribute__((address_space(3))) void*)l,
        16, 0, 0);
}

// ---------------------------------------------------------------------------
// Preamble: x -> hi/lo planes; weights (in_w, xproj_w, out_w) -> hi only.
// ---------------------------------------------------------------------------
#define SG0 524288    // x        granules (K/4 per row)  hi+lo
#define SG1 1048576   // in_w                              hi
#define SG2 65536     // xproj (128 rows pad)              hi
#define SG3 524288    // out_w                             hi
#define SPLIT_GRANULES (SG0 + SG1 + SG2 + SG3)   // 2162688

__global__ __launch_bounds__(256) void split_all(
    const float* __restrict__ x,   const float* __restrict__ in_w,
    const float* __restrict__ xpw, const float* __restrict__ ow,
    ushort_t* __restrict__ xh,   ushort_t* __restrict__ xl,
    ushort_t* __restrict__ iwh,  ushort_t* __restrict__ xph,
    ushort_t* __restrict__ owh)
{
    int g = blockIdx.x * 256 + threadIdx.x;
    const float* src; int K, rows_src; ushort_t *dh, *dl; bool lo;
    if (g < SG0)               { src = x;    K = 1024; rows_src = 2048; dh = xh;  dl = xl; lo = true;  }
    else if ((g -= SG0) < SG1) { src = in_w; K = 1024; rows_src = 4096; dh = iwh; dl = 0;  lo = false; }
    else if ((g -= SG1) < SG2) { src = xpw;  K = 2048; rows_src = 96;   dh = xph; dl = 0;  lo = false; }
    else                       { g -= SG2;   src = ow; K = 2048; rows_src = 1024; dh = owh; dl = 0; lo = false; }

    const int kq = K >> 2;
    const int r = g / kq;
    const int k4 = (g - r * kq) << 2;
    float4 v = make_float4(0.f, 0.f, 0.f, 0.f);
    if (r < rows_src)
        v = *reinterpret_cast<const float4*>(src + (size_t)r * K + k4);
    const unsigned short h0 = f2bf(v.x), h1 = f2bf(v.y), h2 = f2bf(v.z), h3 = f2bf(v.w);
    *reinterpret_cast<ushort4*>(dh + (size_t)r * K + k4) = make_ushort4(h0, h1, h2, h3);
    if (lo) {
        const unsigned short l0 = f2bf(v.x - bf2f(h0)), l1 = f2bf(v.y - bf2f(h1));
        const unsigned short l2 = f2bf(v.z - bf2f(h2)), l3 = f2bf(v.w - bf2f(h3));
        *reinterpret_cast<ushort4*>(dl + (size_t)r * K + k4) = make_ushort4(l0, l1, l2, l3);
    }
}

// ---------------------------------------------------------------------------
// 2-pass bf16 MFMA GEMM (NT): C = (Ah+Al) @ Bh^T, fp32 accum.
// 128xBN tile, BK=64, 4 waves. EPI 2 (in_proj): n0<D_INNER -> fp32 XX;
// else silu -> bf16 SR.
// ---------------------------------------------------------------------------
__device__ __forceinline__ short8 frag_ld(const unsigned short* base, int row, int slot) {
    const char* p = reinterpret_cast<const char*>(base) +
                    row * 128 + (((slot ^ (row & 7)) & 7) << 4);
    return *reinterpret_cast<const short8*>(p);
}

template <int EPI, int BN>
__global__ __launch_bounds__(256) void gemm_bf2(
    const ushort_t* __restrict__ Ahg, const ushort_t* __restrict__ Alg, int lda,
    const ushort_t* __restrict__ Bhg, int ldb,
    float* __restrict__ C, int ldc, size_t czstride,
    ushort_t* __restrict__ SR, int kLen)
{
    constexpr int NJ = BN / 32;
    __shared__ ushort_t Ahs[128 * 64];
    __shared__ ushort_t Als[128 * 64];
    __shared__ ushort_t Bhs[BN * 64];

    const int tid = threadIdx.x;
    const int lane = tid & 63;
    const int w = tid >> 6;
    const int wr = w >> 1, wc = w & 1;
    const int fr = lane & 15, fg = lane >> 4;
    const int m0 = blockIdx.y * 128;
    const int n0 = blockIdx.x * BN;
    const int kOff = blockIdx.z * kLen;
    Ahg += kOff; Alg += kOff; Bhg += kOff;
    C += (size_t)blockIdx.z * czstride;

    f32x4 zero = {0.f, 0.f, 0.f, 0.f};
    f32x4 acc[4][NJ];
#pragma unroll
    for (int i = 0; i < 4; ++i)
#pragma unroll
        for (int j = 0; j < NJ; ++j) acc[i][j] = zero;

    for (int k0 = 0; k0 < kLen; k0 += 64) {
#pragma unroll
        for (int it = 0; it < 4; ++it) {
            const int f = it * 256 + tid;
            const int row = f >> 3;
            const int gc = ((f & 7) ^ (row & 7)) << 3;
            const size_t ga = (size_t)(m0 + row) * lda + k0 + gc;
            gload_lds16(Ahg + ga, &Ahs[f * 8]);
            gload_lds16(Alg + ga, &Als[f * 8]);
        }
#pragma unroll
        for (int it = 0; it < BN / 32; ++it) {
            const int f = it * 256 + tid;
            const int row = f >> 3;
            const int gc = ((f & 7) ^ (row & 7)) << 3;
            const size_t gb = (size_t)(n0 + row) * ldb + k0 + gc;
            gload_lds16(Bhg + gb, &Bhs[f * 8]);
        }
        __syncthreads();

#pragma unroll
        for (int kk = 0; kk < 2; ++kk) {
            short8 ah[4], bh[NJ], al[4];
#pragma unroll
            for (int i = 0; i < 4; ++i)
                ah[i] = frag_ld(Ahs, wr * 64 + i * 16 + fr, kk * 4 + fg);
#pragma unroll
            for (int i = 0; i < NJ; ++i)
                bh[i] = frag_ld(Bhs, wc * (BN / 2) + i * 16 + fr, kk * 4 + fg);
#pragma unroll
            for (int i = 0; i < 4; ++i)
#pragma unroll
                for (int j = 0; j < NJ; ++j)
                    acc[i][j] = __builtin_amdgcn_mfma_f32_16x16x32_bf16(
                        ah[i], bh[j], acc[i][j], 0, 0, 0);
#pragma unroll
            for (int i = 0; i < 4; ++i)
                al[i] = frag_ld(Als, wr * 64 + i * 16 + fr, kk * 4 + fg);
#pragma unroll
            for (int i = 0; i < 4; ++i)
#pragma unroll
                for (int j = 0; j < NJ; ++j)
                    acc[i][j] = __builtin_amdgcn_mfma_f32_16x16x32_bf16(
                        al[i], bh[j], acc[i][j], 0, 0, 0);
        }
        __syncthreads();
    }

#pragma unroll
    for (int i = 0; i < 4; ++i) {
        const int mrow = m0 + wr * 64 + i * 16 + fg * 4;
#pragma unroll
        for (int j = 0; j < NJ; ++j) {
            const int col = n0 + wc * (BN / 2) + j * 16 + fr;
#pragma unroll
            for (int r = 0; r < 4; ++r) {
                float v = acc[i][j][r];
                if constexpr (EPI == 2) {
                    if (n0 < D_INNER) {
                        C[(size_t)(mrow + r) * D_INNER + col] = v;
                    } else {
                        const float sv = v / (1.f + __expf(-v));
                        SR[(size_t)(mrow + r) * D_INNER + col - D_INNER] = f2bf(sv);
                    }
                } else {
                    C[(size_t)(mrow + r) * ldc + col] = v;
                }
            }
        }
    }
}

// ---------------------------------------------------------------------------
// DELTA = softplus(XDBL[:, :64] @ dt_w^T + dt_b), W-in-VGPR fp32 VALU.
// ---------------------------------------------------------------------------
#define DTC 64
#define DTR 64
__global__ __launch_bounds__(256) void dt_softplus(
    const float* __restrict__ XDBL, const float* __restrict__ dtw,
    const float* __restrict__ dtb, float* __restrict__ DELTA)
{
    __shared__ float X[DTR][68];

    const int tid = threadIdx.x;
    const int lane = tid & 63;
    const int wv = tid >> 6;
    const int d = blockIdx.x * DTC + lane;
    const int m0 = blockIdx.y * DTR;

#pragma unroll
    for (int i = 0; i < 4; ++i) {
        const int g = tid + i * 256;
        const int r = g >> 4;
        const int q4 = (g & 15) << 2;
        const float4 v = *reinterpret_cast<const float4*>(
            XDBL + (size_t)(m0 + r) * XDBL_K + q4);
        *reinterpret_cast<float4*>(&X[r][q4]) = v;
    }

    float wreg[DT_RANK];
#pragma unroll
    for (int k4 = 0; k4 < DT_RANK / 4; ++k4) {
        const float4 v = *reinterpret_cast<const float4*>(
            dtw + (size_t)d * DT_RANK + k4 * 4);
        wreg[k4 * 4 + 0] = v.x;
        wreg[k4 * 4 + 1] = v.y;
        wreg[k4 * 4 + 2] = v.z;
        wreg[k4 * 4 + 3] = v.w;
    }
    const float bias = dtb[d];
    __syncthreads();

#pragma unroll
    for (int r = 0; r < DTR / 4; ++r) {
        const int rl = wv * (DTR / 4) + r;
        float a0 = bias, a1 = 0.f, a2 = 0.f, a3 = 0.f;
#pragma unroll
        for (int k = 0; k < DT_RANK; k += 4) {
            const float4 xv = *reinterpret_cast<const float4*>(&X[rl][k]);
            a0 = fmaf(xv.x, wreg[k + 0], a0);
            a1 = fmaf(xv.y, wreg[k + 1], a1);
            a2 = fmaf(xv.z, wreg[k + 2], a2);
            a3 = fmaf(xv.w, wreg[k + 3], a3);
        }
        float acc = (a0 + a1) + (a2 + a3);
        acc = (acc > 20.f) ? acc : log1pf(__expf(acc));
        DELTA[(size_t)(m0 + rl) * D_INNER + d] = acc;
    }
}

// ---------------------------------------------------------------------------
// Causal depthwise conv (k=4) + bias + SiLU -> planar Uh/Ul (for xdbl GEMM).
// ---------------------------------------------------------------------------
__global__ __launch_bounds__(256) void conv_silu(
    const float* __restrict__ XX, const float* __restrict__ cw,
    const float* __restrict__ cb, ushort_t* __restrict__ Uh,
    ushort_t* __restrict__ Ul)
{
    const int idx = blockIdx.x * 256 + threadIdx.x;
    const int d = idx & (D_INNER - 1);
    const int m = idx >> 11;
    const int l = m & (SEQ - 1);

    float acc = cb[d];
#pragma unroll
    for (int j = 0; j < D_CONV; ++j) {
        const int ll = l - (D_CONV - 1) + j;
        if (ll >= 0)
            acc = fmaf(XX[(size_t)(m - (D_CONV - 1) + j) * D_INNER + d],
                       cw[d * D_CONV + j], acc);
    }
    const float s = acc / (1.f + __expf(-acc));
    const unsigned short h = f2bf(s);
    Uh[idx] = h;
    Ul[idx] = f2bf(s - bf2f(h));
}

// ---------------------------------------------------------------------------
// Chunked selective scan, lane = channel; h[16], a[16] in regs. LC=16.
// u computed INLINE from XX via register-rotated causal conv (1 coalesced
// load/step instead of Uh+Ul; exact fp32, identical in both phases).
// ---------------------------------------------------------------------------
__global__ __launch_bounds__(256) void scan_phase1(
    const float* __restrict__ DELTA, const float* __restrict__ XX,
    const float* __restrict__ cw, const float* __restrict__ cb,
    const float* __restrict__ XDBL, const float* __restrict__ A_log,
    float* __restrict__ P, float* __restrict__ HL)
{
    const int tid = threadIdx.x;
    const int d = blockIdx.x * 256 + tid;
    const int c = blockIdx.y;
    const int b = blockIdx.z;

    float a[16];
#pragma unroll
    for (int q = 0; q < 4; ++q) {
        const float4 v = *reinterpret_cast<const float4*>(A_log + (size_t)d * 16 + q * 4);
        a[q * 4 + 0] = -__expf(v.x);
        a[q * 4 + 1] = -__expf(v.y);
        a[q * 4 + 2] = -__expf(v.z);
        a[q * 4 + 3] = -__expf(v.w);
    }
    const float4 cwv = *reinterpret_cast<const float4*>(cw + (size_t)d * 4);
    const float cbd = cb[d];

    const size_t base = (size_t)b * SEQ + (size_t)c * LC;
    // conv history: x of rows base-3, base-2, base-1 (zeros if c==0)
    float xm3 = 0.f, xm2 = 0.f, xm1 = 0.f;
    if (c > 0) {
        xm3 = XX[(base - 3) * D_INNER + d];
        xm2 = XX[(base - 2) * D_INNER + d];
        xm1 = XX[(base - 1) * D_INNER + d];
    }

    float h[16];
#pragma unroll
    for (int n = 0; n < 16; ++n) h[n] = 0.f;
    float sd = 0.f;

#pragma unroll 4
    for (int t = 0; t < LC; ++t) {
        const size_t m = base + t;
        const float delta = DELTA[m * D_INNER + d];
        const float xc = XX[m * D_INNER + d];
        float cacc = cbd;
        cacc = fmaf(xm3, cwv.x, cacc);
        cacc = fmaf(xm2, cwv.y, cacc);
        cacc = fmaf(xm1, cwv.z, cacc);
        cacc = fmaf(xc,  cwv.w, cacc);
        const float u = cacc / (1.f + __expf(-cacc));
        xm3 = xm2; xm2 = xm1; xm1 = xc;

        const float du = delta * u;
        const float* xb = XDBL + m * XDBL_K + DT_RANK;   // wave-uniform
        float bv[16];
#pragma unroll
        for (int n = 0; n < 16; ++n) bv[n] = xb[n];
        sd += delta;
#pragma unroll
        for (int n = 0; n < 16; ++n) {
            const float dA = __expf(delta * a[n]);
            h[n] = fmaf(dA, h[n], du * bv[n]);
        }
    }

    const size_t idx = (size_t)c * SLANES + ((size_t)b * D_INNER + d) * 16;
#pragma unroll
    for (int q = 0; q < 4; ++q) {
        float4 pv, hv;
        pv.x = __expf(a[q * 4 + 0] * sd);
        pv.y = __expf(a[q * 4 + 1] * sd);
        pv.z = __expf(a[q * 4 + 2] * sd);
        pv.w = __expf(a[q * 4 + 3] * sd);
        hv.x = h[q * 4 + 0]; hv.y = h[q * 4 + 1];
        hv.z = h[q * 4 + 2]; hv.w = h[q * 4 + 3];
        *reinterpret_cast<float4*>(&P[idx + q * 4]) = pv;
        *reinterpret_cast<float4*>(&HL[idx + q * 4]) = hv;
    }
}

__global__ __launch_bounds__(256) void scan_phase2(
    float* __restrict__ P, const float* __restrict__ HL)
{
    const int t = blockIdx.x * 256 + threadIdx.x;
    float h = 0.f;
#pragma unroll 8
    for (int c = 0; c < NC; ++c) {
        const size_t idx = (size_t)c * SLANES + t;
        const float p = P[idx];
        const float hl = HL[idx];
        P[idx] = h;
        h = fmaf(p, h, hl);
    }
}

__global__ __launch_bounds__(256) void scan_phase3(
    const float* __restrict__ DELTA, const float* __restrict__ XX,
    const float* __restrict__ cw, const float* __restrict__ cb,
    const float* __restrict__ XDBL, const ushort_t* __restrict__ SR,
    const float* __restrict__ A_log, const float* __restrict__ Dp,
    const float* __restrict__ H0,
    ushort_t* __restrict__ Yh, ushort_t* __restrict__ Yl)
{
    const int tid = threadIdx.x;
    const int d = blockIdx.x * 256 + tid;
    const int c = blockIdx.y;
    const int b = blockIdx.z;

    float a[16];
#pragma unroll
    for (int q = 0; q < 4; ++q) {
        const float4 v = *reinterpret_cast<const float4*>(A_log + (size_t)d * 16 + q * 4);
        a[q * 4 + 0] = -__expf(v.x);
        a[q * 4 + 1] = -__expf(v.y);
        a[q * 4 + 2] = -__expf(v.z);
        a[q * 4 + 3] = -__expf(v.w);
    }
    const float Dd = Dp[d];
    const float4 cwv = *reinterpret_cast<const float4*>(cw + (size_t)d * 4);
    const float cbd = cb[d];

    const size_t base = (size_t)b * SEQ + (size_t)c * LC;
    float xm3 = 0.f, xm2 = 0.f, xm1 = 0.f;
    if (c > 0) {
        xm3 = XX[(base - 3) * D_INNER + d];
        xm2 = XX[(base - 2) * D_INNER + d];
        xm1 = XX[(base - 1) * D_INNER + d];
    }

    float h[16];
    const size_t idx0 = (size_t)c * SLANES + ((size_t)b * D_INNER + d) * 16;
#pragma unroll
    for (int q = 0; q < 4; ++q) {
        const float4 v = *reinterpret_cast<const float4*>(&H0[idx0 + q * 4]);
        h[q * 4 + 0] = v.x; h[q * 4 + 1] = v.y;
        h[q * 4 + 2] = v.z; h[q * 4 + 3] = v.w;
    }

#pragma unroll 4
    for (int t = 0; t < LC; ++t) {
        const size_t m = base + t;
        const float delta = DELTA[m * D_INNER + d];
        const float xc = XX[m * D_INNER + d];
        float cacc = cbd;
        cacc = fmaf(xm3, cwv.x, cacc);
        cacc = fmaf(xm2, cwv.y, cacc);
        cacc = fmaf(xm1, cwv.z, cacc);
        cacc = fmaf(xc,  cwv.w, cacc);
        const float u = cacc / (1.f + __expf(-cacc));
        xm3 = xm2; xm2 = xm1; xm1 = xc;

        const float du = delta * u;
        const float* xb = XDBL + m * XDBL_K + DT_RANK;   // wave-uniform
        float bv[16], cv[16];
#pragma unroll
        for (int n = 0; n < 16; ++n) bv[n] = xb[n];
#pragma unroll
        for (int n = 0; n < 16; ++n) cv[n] = xb[16 + n];

        float y0 = 0.f, y1 = 0.f, y2 = 0.f, y3 = 0.f;
#pragma unroll
        for (int n = 0; n < 4; ++n) {
            const float dA0 = __expf(delta * a[n]);
            const float dA1 = __expf(delta * a[n + 4]);
            const float dA2 = __expf(delta * a[n + 8]);
            const float dA3 = __expf(delta * a[n + 12]);
            h[n]      = fmaf(dA0, h[n],      du * bv[n]);
            h[n + 4]  = fmaf(dA1, h[n + 4],  du * bv[n + 4]);
            h[n + 8]  = fmaf(dA2, h[n + 8],  du * bv[n + 8]);
            h[n + 12] = fmaf(dA3, h[n + 12], du * bv[n + 12]);
            y0 = fmaf(h[n],      cv[n],      y0);
            y1 = fmaf(h[n + 4],  cv[n + 4],  y1);
            y2 = fmaf(h[n + 8],  cv[n + 8],  y2);
            y3 = fmaf(h[n + 12], cv[n + 12], y3);
        }
        const float y = (y0 + y1) + (y2 + y3) + u * Dd;
        const float sr = bf2f(SR[m * D_INNER + d]);
        const float yg = y * sr;
        const unsigned short hh = f2bf(yg);
        Yh[m * D_INNER + d] = hh;
        Yl[m * D_INNER + d] = f2bf(yg - bf2f(hh));
    }
}

// ---------------------------------------------------------------------------
// split-K reductions
// ---------------------------------------------------------------------------
__global__ __launch_bounds__(256) void reduce_xdbl(
    const float* __restrict__ PP, float* __restrict__ XDBL)
{
    const int t = blockIdx.x * 256 + threadIdx.x;
    const int m = t / XDBL_K;
    const int n = t - m * XDBL_K;
    float s = 0.f;
#pragma unroll
    for (int z = 0; z < 16; ++z)
        s += PP[(size_t)z * MROWS * 128 + (size_t)m * 128 + n];
    XDBL[t] = s;
}

__global__ __launch_bounds__(256) void reduce_out(
    const float* __restrict__ OP, float* __restrict__ out)
{
    const int t = blockIdx.x * 256 + threadIdx.x;
    const float4 a = *reinterpret_cast<const float4*>(OP + (size_t)t * 4);
    const float4 b = *reinterpret_cast<const float4*>(OP + (size_t)MROWS * DIM + (size_t)t * 4);
    float4 r;
    r.x = a.x + b.x; r.y = a.y + b.y; r.z = a.z + b.z; r.w = a.w + b.w;
    *reinterpret_cast<float4*>(out + (size_t)t * 4) = r;
}

// ---------------------------------------------------------------------------
extern "C" void kernel_launch(void* const* d_in, const int* in_sizes, int n_in,
                              void* d_out, int out_size, void* d_ws, size_t ws_size,
                              hipStream_t stream)
{
    const float* x       = (const float*)d_in[0];
    const float* in_w    = (const float*)d_in[1];
    const float* conv_w  = (const float*)d_in[2];
    const float* conv_b  = (const float*)d_in[3];
    const float* xproj_w = (const float*)d_in[4];
    const float* dt_w    = (const float*)d_in[5];
    const float* dt_b    = (const float*)d_in[6];
    const float* A_log   = (const float*)d_in[7];
    const float* Dp      = (const float*)d_in[8];
    const float* out_w   = (const float*)d_in[9];
    float* out = (float*)d_out;

    const size_t MF = 1024 * 1024;
    float* WF    = (float*)d_ws;
    float* XX    = WF;                 // [0,4M) xx half fp32 (live through scan3)
    ushort_t* SRb = (ushort_t*)(WF + 4 * MF);   // [4,6M) silu(res) bf16
    float* OP    = WF + 21 * MF + 16 * MF;      // placeholder, set below
    float* DELTA = WF + 8 * MF;        // [8,12M)
    float* XDBL  = WF + 12 * MF;       // 2048*96 floats
    float* PP    = WF + 13 * MF;       // [13,17M) xdbl partials (dead before scan)
    float* P     = WF + 13 * MF;       // [13,17M) NC=64 -> 4M floats
    float* HL    = WF + 17 * MF;       // [17,21M); Yl reuses after phase2
    OP           = WF + 6 * MF;        // [6,8M)+... need 4M floats: use [6,8M)? too small
    // out partials need 2 x 2M = 4M floats; place at [33,37M) past bf16 pool end

    // bf16 planar buffers (ushort units), base at 21M floats
    ushort_t* UB  = (ushort_t*)(WF + 21 * MF);
    ushort_t* xh  = UB;                         // 2M  } dead after in_proj
    ushort_t* xl  = UB + 2 * MF;                // 2M  }
    ushort_t* iwh = UB + 4 * MF;                // 4M  }
    ushort_t* Uh  = UB;                         // 4M (conv output; xdbl GEMM only)
    ushort_t* Ul  = UB + 4 * MF;                // 4M
    ushort_t* Yh  = UB + 8 * MF;                // 4M (scan3 output)
    ushort_t* Yl  = (ushort_t*)(WF + 17 * MF);  // 4M ushorts in dead HL region
    ushort_t* xph = UB + 12 * MF;               // 256K (128 x 2048 padded)
    ushort_t* owh = xph + 256 * 1024;           // 2M
    OP = WF + 21 * MF + 8 * MF;                 // [29,33M) floats: after Yh region
                                                // (UB+16M ushorts = WF+29M floats)

    const dim3 blk(256);

    // 0) split: x -> hi/lo, weights -> hi
    split_all<<<SPLIT_GRANULES / 256, blk, 0, stream>>>(
        x, in_w, xproj_w, out_w, xh, xl, iwh, xph, owh);

    // 1) in_proj: XX (fp32) + SR (bf16 silu(res)) = X @ in_w^T
    gemm_bf2<2, 128><<<dim3(NPROJ / 128, MROWS / 128, 1), blk, 0, stream>>>(
        xh, xl, DIM, iwh, DIM, XX, D_INNER, 0, SRb, DIM);

    // 2) conv + silu -> Uh/Ul (consumed only by xdbl GEMM)
    conv_silu<<<(MROWS * D_INNER) / 256, blk, 0, stream>>>(XX, conv_w, conv_b, Uh, Ul);

    // 3) x_dbl = U @ xproj_w^T (N 96->128 pad, split-K=16, kLen=128)
    gemm_bf2<0, 128><<<dim3(1, MROWS / 128, 16), blk, 0, stream>>>(
        Uh, Ul, D_INNER, xph, D_INNER, PP, 128, (size_t)MROWS * 128, nullptr, D_INNER / 16);
    reduce_xdbl<<<(MROWS * XDBL_K) / 256, blk, 0, stream>>>(PP, XDBL);

    // 4) DELTA = softplus(XDBL[:, :64] @ dt_w^T + dt_b) — W-in-VGPR fp32 VALU
    dt_softplus<<<dim3(D_INNER / DTC, MROWS / DTR), blk, 0, stream>>>(
        XDBL, dt_w, dt_b, DELTA);

    // 5) chunked selective scan (LC=16); u recomputed inline from XX
    scan_phase1<<<dim3(D_INNER / 256, NC, BATCH), blk, 0, stream>>>(
        DELTA, XX, conv_w, conv_b, XDBL, A_log, P, HL);
    scan_phase2<<<SLANES / 256, blk, 0, stream>>>(P, HL);
    scan_phase3<<<dim3(D_INNER / 256, NC, BATCH), blk, 0, stream>>>(
        DELTA, XX, conv_w, conv_b, XDBL, SRb, A_log, Dp, P, Yh, Yl);

    // 6) out = Y @ out_w^T (BN=64 tile, split-K=2, 512 blocks)
    gemm_bf2<0, 64><<<dim3(DIM / 64, MROWS / 128, 2), blk, 0, stream>>>(
        Yh, Yl, D_INNER, owh, D_INNER, OP, DIM, (size_t)MROWS * DIM, nullptr, D_INNER / 2);
    reduce_out<<<(MROWS * DIM / 4) / 256, blk, 0, stream>>>(OP, out);
}

// Round 18
// 209.032 us; speedup vs baseline: 1.0233x; 1.0233x over previous
//
#include <hip/hip_runtime.h>
#include <hip/hip_bf16.h>
#include <stdint.h>

// Shapes
#define DIM      1024
#define D_STATE  16
#define D_CONV   4
#define D_INNER  2048
#define DT_RANK  64
#define BATCH    2
#define SEQ      1024
#define MROWS    (BATCH * SEQ)            // 2048
#define NPROJ    (2 * D_INNER)            // 4096
#define XDBL_K   (DT_RANK + 2 * D_STATE)  // 96

// chunked scan
#define LC       16
#define NC       (SEQ / LC)               // 64
#define SLANES   (BATCH * D_INNER * D_STATE) // 65536

typedef __attribute__((ext_vector_type(8))) short short8;
typedef __attribute__((ext_vector_type(4))) float f32x4;
typedef unsigned short ushort_t;

__device__ __forceinline__ unsigned short f2bf(float f) {
    __hip_bfloat16 b = __float2bfloat16(f);
    return *reinterpret_cast<unsigned short*>(&b);
}
__device__ __forceinline__ float bf2f(unsigned short u) {
    __hip_bfloat16 b;
    *reinterpret_cast<unsigned short*>(&b) = u;
    return __bfloat162float(b);
}

__device__ __forceinline__ void gload_lds16(const unsigned short* g, unsigned short* l) {
    __builtin_amdgcn_global_load_lds(
        (const __attribute__((address_space(1))) void*)g,
        (__attribute__((address_space(3))) void*)l,
        16, 0, 0);
}

// ---------------------------------------------------------------------------
// Preamble: x -> hi/lo planes; weights (in_w, xproj_w, out_w) -> hi only.
// ---------------------------------------------------------------------------
#define SG0 524288    // x        granules (K/4 per row)  hi+lo
#define SG1 1048576   // in_w                              hi
#define SG2 65536     // xproj (128 rows pad)              hi
#define SG3 524288    // out_w                             hi
#define SPLIT_GRANULES (SG0 + SG1 + SG2 + SG3)   // 2162688

__global__ __launch_bounds__(256) void split_all(
    const float* __restrict__ x,   const float* __restrict__ in_w,
    const float* __restrict__ xpw, const float* __restrict__ ow,
    ushort_t* __restrict__ xh,   ushort_t* __restrict__ xl,
    ushort_t* __restrict__ iwh,  ushort_t* __restrict__ xph,
    ushort_t* __restrict__ owh)
{
    int g = blockIdx.x * 256 + threadIdx.x;
    const float* src; int K, rows_src; ushort_t *dh, *dl; bool lo;
    if (g < SG0)               { src = x;    K = 1024; rows_src = 2048; dh = xh;  dl = xl; lo = true;  }
    else if ((g -= SG0) < SG1) { src = in_w; K = 1024; rows_src = 4096; dh = iwh; dl = 0;  lo = false; }
    else if ((g -= SG1) < SG2) { src = xpw;  K = 2048; rows_src = 96;   dh = xph; dl = 0;  lo = false; }
    else                       { g -= SG2;   src = ow; K = 2048; rows_src = 1024; dh = owh; dl = 0; lo = false; }

    const int kq = K >> 2;
    const int r = g / kq;
    const int k4 = (g - r * kq) << 2;
    float4 v = make_float4(0.f, 0.f, 0.f, 0.f);
    if (r < rows_src)
        v = *reinterpret_cast<const float4*>(src + (size_t)r * K + k4);
    const unsigned short h0 = f2bf(v.x), h1 = f2bf(v.y), h2 = f2bf(v.z), h3 = f2bf(v.w);
    *reinterpret_cast<ushort4*>(dh + (size_t)r * K + k4) = make_ushort4(h0, h1, h2, h3);
    if (lo) {
        const unsigned short l0 = f2bf(v.x - bf2f(h0)), l1 = f2bf(v.y - bf2f(h1));
        const unsigned short l2 = f2bf(v.z - bf2f(h2)), l3 = f2bf(v.w - bf2f(h3));
        *reinterpret_cast<ushort4*>(dl + (size_t)r * K + k4) = make_ushort4(l0, l1, l2, l3);
    }
}

// ---------------------------------------------------------------------------
// 2-pass bf16 MFMA GEMM (NT): C = (Ah+Al) @ Bh^T, fp32 accum.
// 128xBN tile, BK=64, 4 waves. BN=128: 48KB LDS (3 blk/CU). BN=64: 40KB
// (4 blk/CU). EPI 2 (in_proj): n0<D_INNER -> fp32 XX; else silu -> bf16 SR.
// ---------------------------------------------------------------------------
__device__ __forceinline__ short8 frag_ld(const unsigned short* base, int row, int slot) {
    const char* p = reinterpret_cast<const char*>(base) +
                    row * 128 + (((slot ^ (row & 7)) & 7) << 4);
    return *reinterpret_cast<const short8*>(p);
}

template <int EPI, int BN>
__global__ __launch_bounds__(256) void gemm_bf2(
    const ushort_t* __restrict__ Ahg, const ushort_t* __restrict__ Alg, int lda,
    const ushort_t* __restrict__ Bhg, int ldb,
    float* __restrict__ C, int ldc, size_t czstride,
    ushort_t* __restrict__ SR, int kLen)
{
    constexpr int NJ = BN / 32;          // col frags per wave
    __shared__ ushort_t Ahs[128 * 64];
    __shared__ ushort_t Als[128 * 64];
    __shared__ ushort_t Bhs[BN * 64];

    const int tid = threadIdx.x;
    const int lane = tid & 63;
    const int w = tid >> 6;
    const int wr = w >> 1, wc = w & 1;
    const int fr = lane & 15, fg = lane >> 4;
    const int m0 = blockIdx.y * 128;
    const int n0 = blockIdx.x * BN;
    const int kOff = blockIdx.z * kLen;
    Ahg += kOff; Alg += kOff; Bhg += kOff;
    C += (size_t)blockIdx.z * czstride;

    f32x4 zero = {0.f, 0.f, 0.f, 0.f};
    f32x4 acc[4][NJ];
#pragma unroll
    for (int i = 0; i < 4; ++i)
#pragma unroll
        for (int j = 0; j < NJ; ++j) acc[i][j] = zero;

    for (int k0 = 0; k0 < kLen; k0 += 64) {
#pragma unroll
        for (int it = 0; it < 4; ++it) {
            const int f = it * 256 + tid;
            const int row = f >> 3;
            const int gc = ((f & 7) ^ (row & 7)) << 3;
            const size_t ga = (size_t)(m0 + row) * lda + k0 + gc;
            gload_lds16(Ahg + ga, &Ahs[f * 8]);
            gload_lds16(Alg + ga, &Als[f * 8]);
        }
#pragma unroll
        for (int it = 0; it < BN / 32; ++it) {
            const int f = it * 256 + tid;
            const int row = f >> 3;
            const int gc = ((f & 7) ^ (row & 7)) << 3;
            const size_t gb = (size_t)(n0 + row) * ldb + k0 + gc;
            gload_lds16(Bhg + gb, &Bhs[f * 8]);
        }
        __syncthreads();

#pragma unroll
        for (int kk = 0; kk < 2; ++kk) {
            short8 ah[4], bh[NJ], al[4];
#pragma unroll
            for (int i = 0; i < 4; ++i)
                ah[i] = frag_ld(Ahs, wr * 64 + i * 16 + fr, kk * 4 + fg);
#pragma unroll
            for (int i = 0; i < NJ; ++i)
                bh[i] = frag_ld(Bhs, wc * (BN / 2) + i * 16 + fr, kk * 4 + fg);
#pragma unroll
            for (int i = 0; i < 4; ++i)
#pragma unroll
                for (int j = 0; j < NJ; ++j)
                    acc[i][j] = __builtin_amdgcn_mfma_f32_16x16x32_bf16(
                        ah[i], bh[j], acc[i][j], 0, 0, 0);
#pragma unroll
            for (int i = 0; i < 4; ++i)
                al[i] = frag_ld(Als, wr * 64 + i * 16 + fr, kk * 4 + fg);
#pragma unroll
            for (int i = 0; i < 4; ++i)
#pragma unroll
                for (int j = 0; j < NJ; ++j)
                    acc[i][j] = __builtin_amdgcn_mfma_f32_16x16x32_bf16(
                        al[i], bh[j], acc[i][j], 0, 0, 0);
        }
        __syncthreads();
    }

#pragma unroll
    for (int i = 0; i < 4; ++i) {
        const int mrow = m0 + wr * 64 + i * 16 + fg * 4;
#pragma unroll
        for (int j = 0; j < NJ; ++j) {
            const int col = n0 + wc * (BN / 2) + j * 16 + fr;
#pragma unroll
            for (int r = 0; r < 4; ++r) {
                float v = acc[i][j][r];
                if constexpr (EPI == 2) {
                    if (n0 < D_INNER) {
                        C[(size_t)(mrow + r) * D_INNER + col] = v;
                    } else {
                        const float sv = v / (1.f + __expf(-v));
                        SR[(size_t)(mrow + r) * D_INNER + col - D_INNER] = f2bf(sv);
                    }
                } else {
                    C[(size_t)(mrow + r) * ldc + col] = v;
                }
            }
        }
    }
}

// ---------------------------------------------------------------------------
// DELTA = softplus(XDBL[:, :64] @ dt_w^T + dt_b), W-in-VGPR fp32 VALU.
// ---------------------------------------------------------------------------
#define DTC 64
#define DTR 64
__global__ __launch_bounds__(256) void dt_softplus(
    const float* __restrict__ XDBL, const float* __restrict__ dtw,
    const float* __restrict__ dtb, float* __restrict__ DELTA)
{
    __shared__ float X[DTR][68];

    const int tid = threadIdx.x;
    const int lane = tid & 63;
    const int wv = tid >> 6;
    const int d = blockIdx.x * DTC + lane;
    const int m0 = blockIdx.y * DTR;

#pragma unroll
    for (int i = 0; i < 4; ++i) {
        const int g = tid + i * 256;
        const int r = g >> 4;
        const int q4 = (g & 15) << 2;
        const float4 v = *reinterpret_cast<const float4*>(
            XDBL + (size_t)(m0 + r) * XDBL_K + q4);
        *reinterpret_cast<float4*>(&X[r][q4]) = v;
    }

    float wreg[DT_RANK];
#pragma unroll
    for (int k4 = 0; k4 < DT_RANK / 4; ++k4) {
        const float4 v = *reinterpret_cast<const float4*>(
            dtw + (size_t)d * DT_RANK + k4 * 4);
        wreg[k4 * 4 + 0] = v.x;
        wreg[k4 * 4 + 1] = v.y;
        wreg[k4 * 4 + 2] = v.z;
        wreg[k4 * 4 + 3] = v.w;
    }
    const float bias = dtb[d];
    __syncthreads();

#pragma unroll
    for (int r = 0; r < DTR / 4; ++r) {
        const int rl = wv * (DTR / 4) + r;
        float a0 = bias, a1 = 0.f, a2 = 0.f, a3 = 0.f;
#pragma unroll
        for (int k = 0; k < DT_RANK; k += 4) {
            const float4 xv = *reinterpret_cast<const float4*>(&X[rl][k]);
            a0 = fmaf(xv.x, wreg[k + 0], a0);
            a1 = fmaf(xv.y, wreg[k + 1], a1);
            a2 = fmaf(xv.z, wreg[k + 2], a2);
            a3 = fmaf(xv.w, wreg[k + 3], a3);
        }
        float acc = (a0 + a1) + (a2 + a3);
        acc = (acc > 20.f) ? acc : log1pf(__expf(acc));
        DELTA[(size_t)(m0 + rl) * D_INNER + d] = acc;
    }
}

// ---------------------------------------------------------------------------
// Causal depthwise conv (k=4) + bias + SiLU -> planar Uh/Ul. Reads XX.
// ---------------------------------------------------------------------------
__global__ __launch_bounds__(256) void conv_silu(
    const float* __restrict__ XX, const float* __restrict__ cw,
    const float* __restrict__ cb, ushort_t* __restrict__ Uh,
    ushort_t* __restrict__ Ul)
{
    const int idx = blockIdx.x * 256 + threadIdx.x;
    const int d = idx & (D_INNER - 1);
    const int m = idx >> 11;
    const int l = m & (SEQ - 1);

    float acc = cb[d];
#pragma unroll
    for (int j = 0; j < D_CONV; ++j) {
        const int ll = l - (D_CONV - 1) + j;
        if (ll >= 0)
            acc = fmaf(XX[(size_t)(m - (D_CONV - 1) + j) * D_INNER + d],
                       cw[d * D_CONV + j], acc);
    }
    const float s = acc / (1.f + __expf(-acc));
    const unsigned short h = f2bf(s);
    Uh[idx] = h;
    Ul[idx] = f2bf(s - bf2f(h));
}

// ---------------------------------------------------------------------------
// Chunked selective scan, lane = channel; h[16], a[16] in regs. LC=16.
// ---------------------------------------------------------------------------
__global__ __launch_bounds__(256) void scan_phase1(
    const float* __restrict__ DELTA, const ushort_t* __restrict__ Uh,
    const ushort_t* __restrict__ Ul, const float* __restrict__ XDBL,
    const float* __restrict__ A_log, float* __restrict__ P,
    float* __restrict__ HL)
{
    const int tid = threadIdx.x;
    const int d = blockIdx.x * 256 + tid;
    const int c = blockIdx.y;
    const int b = blockIdx.z;

    float a[16];
#pragma unroll
    for (int q = 0; q < 4; ++q) {
        const float4 v = *reinterpret_cast<const float4*>(A_log + (size_t)d * 16 + q * 4);
        a[q * 4 + 0] = -__expf(v.x);
        a[q * 4 + 1] = -__expf(v.y);
        a[q * 4 + 2] = -__expf(v.z);
        a[q * 4 + 3] = -__expf(v.w);
    }
    float h[16];
#pragma unroll
    for (int n = 0; n < 16; ++n) h[n] = 0.f;
    float sd = 0.f;
    const size_t base = (size_t)b * SEQ + (size_t)c * LC;

#pragma unroll 4
    for (int t = 0; t < LC; ++t) {
        const size_t m = base + t;
        const float delta = DELTA[m * D_INNER + d];
        const float u = bf2f(Uh[m * D_INNER + d]) + bf2f(Ul[m * D_INNER + d]);
        const float du = delta * u;
        const float* xb = XDBL + m * XDBL_K + DT_RANK;   // wave-uniform
        float bv[16];
#pragma unroll
        for (int n = 0; n < 16; ++n) bv[n] = xb[n];
        sd += delta;
#pragma unroll
        for (int n = 0; n < 16; ++n) {
            const float dA = __expf(delta * a[n]);
            h[n] = fmaf(dA, h[n], du * bv[n]);
        }
    }

    const size_t idx = (size_t)c * SLANES + ((size_t)b * D_INNER + d) * 16;
#pragma unroll
    for (int q = 0; q < 4; ++q) {
        float4 pv, hv;
        pv.x = __expf(a[q * 4 + 0] * sd);
        pv.y = __expf(a[q * 4 + 1] * sd);
        pv.z = __expf(a[q * 4 + 2] * sd);
        pv.w = __expf(a[q * 4 + 3] * sd);
        hv.x = h[q * 4 + 0]; hv.y = h[q * 4 + 1];
        hv.z = h[q * 4 + 2]; hv.w = h[q * 4 + 3];
        *reinterpret_cast<float4*>(&P[idx + q * 4]) = pv;
        *reinterpret_cast<float4*>(&HL[idx + q * 4]) = hv;
    }
}

__global__ __launch_bounds__(256) void scan_phase2(
    float* __restrict__ P, const float* __restrict__ HL)
{
    const int t = blockIdx.x * 256 + threadIdx.x;
    float h = 0.f;
#pragma unroll 8
    for (int c = 0; c < NC; ++c) {
        const size_t idx = (size_t)c * SLANES + t;
        const float p = P[idx];
        const float hl = HL[idx];
        P[idx] = h;
        h = fmaf(p, h, hl);
    }
}

__global__ __launch_bounds__(256) void scan_phase3(
    const float* __restrict__ DELTA, const ushort_t* __restrict__ Uh,
    const ushort_t* __restrict__ Ul, const float* __restrict__ XDBL,
    const ushort_t* __restrict__ SR, const float* __restrict__ A_log,
    const float* __restrict__ Dp, const float* __restrict__ H0,
    ushort_t* __restrict__ Yh, ushort_t* __restrict__ Yl)
{
    const int tid = threadIdx.x;
    const int d = blockIdx.x * 256 + tid;
    const int c = blockIdx.y;
    const int b = blockIdx.z;

    float a[16];
#pragma unroll
    for (int q = 0; q < 4; ++q) {
        const float4 v = *reinterpret_cast<const float4*>(A_log + (size_t)d * 16 + q * 4);
        a[q * 4 + 0] = -__expf(v.x);
        a[q * 4 + 1] = -__expf(v.y);
        a[q * 4 + 2] = -__expf(v.z);
        a[q * 4 + 3] = -__expf(v.w);
    }
    const float Dd = Dp[d];

    float h[16];
    const size_t idx0 = (size_t)c * SLANES + ((size_t)b * D_INNER + d) * 16;
#pragma unroll
    for (int q = 0; q < 4; ++q) {
        const float4 v = *reinterpret_cast<const float4*>(&H0[idx0 + q * 4]);
        h[q * 4 + 0] = v.x; h[q * 4 + 1] = v.y;
        h[q * 4 + 2] = v.z; h[q * 4 + 3] = v.w;
    }
    const size_t base = (size_t)b * SEQ + (size_t)c * LC;

#pragma unroll 4
    for (int t = 0; t < LC; ++t) {
        const size_t m = base + t;
        const float delta = DELTA[m * D_INNER + d];
        const float u = bf2f(Uh[m * D_INNER + d]) + bf2f(Ul[m * D_INNER + d]);
        const float du = delta * u;
        const float* xb = XDBL + m * XDBL_K + DT_RANK;   // wave-uniform
        float bv[16], cv[16];
#pragma unroll
        for (int n = 0; n < 16; ++n) bv[n] = xb[n];
#pragma unroll
        for (int n = 0; n < 16; ++n) cv[n] = xb[16 + n];

        float y0 = 0.f, y1 = 0.f, y2 = 0.f, y3 = 0.f;
#pragma unroll
        for (int n = 0; n < 4; ++n) {
            const float dA0 = __expf(delta * a[n]);
            const float dA1 = __expf(delta * a[n + 4]);
            const float dA2 = __expf(delta * a[n + 8]);
            const float dA3 = __expf(delta * a[n + 12]);
            h[n]      = fmaf(dA0, h[n],      du * bv[n]);
            h[n + 4]  = fmaf(dA1, h[n + 4],  du * bv[n + 4]);
            h[n + 8]  = fmaf(dA2, h[n + 8],  du * bv[n + 8]);
            h[n + 12] = fmaf(dA3, h[n + 12], du * bv[n + 12]);
            y0 = fmaf(h[n],      cv[n],      y0);
            y1 = fmaf(h[n + 4],  cv[n + 4],  y1);
            y2 = fmaf(h[n + 8],  cv[n + 8],  y2);
            y3 = fmaf(h[n + 12], cv[n + 12], y3);
        }
        const float y = (y0 + y1) + (y2 + y3) + u * Dd;
        const float sr = bf2f(SR[m * D_INNER + d]);
        const float yg = y * sr;
        const unsigned short hh = f2bf(yg);
        Yh[m * D_INNER + d] = hh;
        Yl[m * D_INNER + d] = f2bf(yg - bf2f(hh));
    }
}

// ---------------------------------------------------------------------------
// split-K reductions
// ---------------------------------------------------------------------------
__global__ __launch_bounds__(256) void reduce_xdbl(
    const float* __restrict__ PP, float* __restrict__ XDBL)
{
    const int t = blockIdx.x * 256 + threadIdx.x;
    const int m = t / XDBL_K;
    const int n = t - m * XDBL_K;
    float s = 0.f;
#pragma unroll
    for (int z = 0; z < 16; ++z)
        s += PP[(size_t)z * MROWS * 128 + (size_t)m * 128 + n];
    XDBL[t] = s;
}

__global__ __launch_bounds__(256) void reduce_out(
    const float* __restrict__ OP, float* __restrict__ out)
{
    const int t = blockIdx.x * 256 + threadIdx.x;
    const float4 a = *reinterpret_cast<const float4*>(OP + (size_t)t * 4);
    const float4 b = *reinterpret_cast<const float4*>(OP + (size_t)MROWS * DIM + (size_t)t * 4);
    float4 r;
    r.x = a.x + b.x; r.y = a.y + b.y; r.z = a.z + b.z; r.w = a.w + b.w;
    *reinterpret_cast<float4*>(out + (size_t)t * 4) = r;
}

// ---------------------------------------------------------------------------
extern "C" void kernel_launch(void* const* d_in, const int* in_sizes, int n_in,
                              void* d_out, int out_size, void* d_ws, size_t ws_size,
                              hipStream_t stream)
{
    const float* x       = (const float*)d_in[0];
    const float* in_w    = (const float*)d_in[1];
    const float* conv_w  = (const float*)d_in[2];
    const float* conv_b  = (const float*)d_in[3];
    const float* xproj_w = (const float*)d_in[4];
    const float* dt_w    = (const float*)d_in[5];
    const float* dt_b    = (const float*)d_in[6];
    const float* A_log   = (const float*)d_in[7];
    const float* Dp      = (const float*)d_in[8];
    const float* out_w   = (const float*)d_in[9];
    float* out = (float*)d_out;

    const size_t MF = 1024 * 1024;
    float* WF    = (float*)d_ws;
    float* XX    = WF;                 // [0,4M) xx half fp32; OP reuses after conv
    ushort_t* SRb = (ushort_t*)(WF + 4 * MF);   // [4,6M) silu(res) bf16
    float* DELTA = WF + 8 * MF;        // [8,12M)
    float* XDBL  = WF + 12 * MF;       // 2048*96 floats
    float* PP    = WF + 13 * MF;       // [13,17M) xdbl partials (dead before scan)
    float* P     = WF + 13 * MF;       // [13,17M) NC=64 -> 4M floats
    float* HL    = WF + 17 * MF;       // [17,21M); Yl reuses after phase2
    float* OP    = WF;                 // out partials, 2 x 2M floats = [0,4M)

    // bf16 planar buffers (ushort units), base at 21M floats
    ushort_t* UB  = (ushort_t*)(WF + 21 * MF);
    ushort_t* xh  = UB;                         // 2M  } dead after in_proj
    ushort_t* xl  = UB + 2 * MF;                // 2M  }
    ushort_t* iwh = UB + 4 * MF;                // 4M  }
    ushort_t* Uh  = UB;                         // 4M (conv output)
    ushort_t* Ul  = UB + 4 * MF;                // 4M
    ushort_t* Yh  = UB + 8 * MF;                // 4M (scan3 output)
    ushort_t* Yl  = (ushort_t*)(WF + 17 * MF);  // 4M ushorts in dead HL region
    ushort_t* xph = UB + 12 * MF;               // 256K (128 x 2048 padded)
    ushort_t* owh = xph + 256 * 1024;           // 2M

    const dim3 blk(256);

    // 0) split: x -> hi/lo, weights -> hi
    split_all<<<SPLIT_GRANULES / 256, blk, 0, stream>>>(
        x, in_w, xproj_w, out_w, xh, xl, iwh, xph, owh);

    // 1) in_proj: XX (fp32) + SR (bf16 silu(res)) = X @ in_w^T
    gemm_bf2<2, 128><<<dim3(NPROJ / 128, MROWS / 128, 1), blk, 0, stream>>>(
        xh, xl, DIM, iwh, DIM, XX, D_INNER, 0, SRb, DIM);

    // 2) conv + silu -> Uh/Ul
    conv_silu<<<(MROWS * D_INNER) / 256, blk, 0, stream>>>(XX, conv_w, conv_b, Uh, Ul);

    // 3) x_dbl = U @ xproj_w^T (N 96->128 pad, split-K=16, kLen=128)
    gemm_bf2<0, 128><<<dim3(1, MROWS / 128, 16), blk, 0, stream>>>(
        Uh, Ul, D_INNER, xph, D_INNER, PP, 128, (size_t)MROWS * 128, nullptr, D_INNER / 16);
    reduce_xdbl<<<(MROWS * XDBL_K) / 256, blk, 0, stream>>>(PP, XDBL);

    // 4) DELTA = softplus(XDBL[:, :64] @ dt_w^T + dt_b) — W-in-VGPR fp32 VALU
    dt_softplus<<<dim3(D_INNER / DTC, MROWS / DTR), blk, 0, stream>>>(
        XDBL, dt_w, dt_b, DELTA);

    // 5) chunked selective scan (LC=16)
    scan_phase1<<<dim3(D_INNER / 256, NC, BATCH), blk, 0, stream>>>(
        DELTA, Uh, Ul, XDBL, A_log, P, HL);
    scan_phase2<<<SLANES / 256, blk, 0, stream>>>(P, HL);
    scan_phase3<<<dim3(D_INNER / 256, NC, BATCH), blk, 0, stream>>>(
        DELTA, Uh, Ul, XDBL, SRb, A_log, Dp, P, Yh, Yl);

    // 6) out = Y @ out_w^T (BN=64 tile, split-K=2, 512 blocks, 4 blk/CU)
    gemm_bf2<0, 64><<<dim3(DIM / 64, MROWS / 128, 2), blk, 0, stream>>>(
        Yh, Yl, D_INNER, owh, D_INNER, OP, DIM, (size_t)MROWS * DIM, nullptr, D_INNER / 2);
    reduce_out<<<(MROWS * DIM / 4) / 256, blk, 0, stream>>>(OP, out);
}